// Round 1
// baseline (71.973 us; speedup 1.0000x reference)
//
#include <hip/hip_runtime.h>

// Problem constants (from setup_inputs): B=4, N=8192, M=8192, D=3, fp32.
constexpr int B = 4;
constexpr int N = 8192;
constexpr int M = 8192;

constexpr int QB     = 64;          // queries per block = 2 mfma column sets
constexpr int WAVES  = 4;           // waves per block (256 threads)
constexpr int QTILES = N / QB;      // 128 -> grid = B*128 = 512 = 2 blocks/CU
constexpr int MPW    = M / WAVES;   // 2048 points per wave
constexpr int TILES  = MPW / 32;    // 64 A-tiles per wave

typedef __bf16 bf16x8 __attribute__((ext_vector_type(8)));
typedef float  f32x16 __attribute__((ext_vector_type(16)));

union FragU { uint4 u; bf16x8 b; };

// ---------------------------------------------------------------------------
// Fused single kernel, NO workspace, NO prep pass, NO atomics.
// Theory: the 256 MiB d_ws re-poison fill (~40 us @ 6.8 TB/s, seen as
// fillBufferAligned in rocprof) sits on the timed path because the previous
// design wrote wtab into d_ws. A-fragments are now built on the fly.
//
// K-slot packing (mfma_f32_32x32x16_bf16, A rows = points, B cols = queries):
//   k0..3 : A=(ph0,ph0,pl0,pl0)  B=(ah0,al0,ah0,al0)  -> (ph0+pl0)(ah0+al0)
//   k4..7 : dim 1   k8..11: dim 2   k12,13: A=(sh,sl) B=(1,1) -> ||p||^2
//   k14,15: 0         (p' = -2p, everything split bf16 hi/lo)
// acc[row=point][col=query] = -2 a.p + ||p||^2
//
// hi/lo split uses TRUNCATION (not RNE): t = u & 0xFFFF0000 keeps |t| <= |v|
// and the low term captures the residual exactly to bf16 precision, so the
// dropped error is O(2^-16) relative — negligible vs the 6.75e-2 threshold.
// pk(h,h) = t | (t>>16) is 2 ops; no rounding adds.
// ---------------------------------------------------------------------------

// (pk(h,h), pk(l,l)) for v — both bf16 halves replicated into a dword.
__device__ inline void split_rep(float v, unsigned& hh, unsigned& ll) {
    const unsigned u = __float_as_uint(v);
    const unsigned t = u & 0xFFFF0000u;
    hh = t | (t >> 16);
    const unsigned r = __float_as_uint(v - __uint_as_float(t)) & 0xFFFF0000u;
    ll = r | (r >> 16);
}

// pk(hi_split, lo_split) for v: h | (l<<16).
__device__ inline unsigned split_pair(float v) {
    const unsigned u = __float_as_uint(v);
    const unsigned t = u & 0xFFFF0000u;
    const unsigned r = __float_as_uint(v - __uint_as_float(t)) & 0xFFFF0000u;
    return (t >> 16) | r;
}

// B fragment (queries): this lane's column q, k-half h.
__device__ inline FragU make_bfrag(const float* __restrict__ a3, int h, float& sq_a) {
    const float a0 = a3[0], a1 = a3[1], a2 = a3[2];
    sq_a = fmaf(a0, a0, fmaf(a1, a1, a2 * a2));
    const unsigned d0 = split_pair(a0);
    const unsigned d1 = split_pair(a1);
    const unsigned d2 = split_pair(a2);
    FragU bq;
    const unsigned dA = h ? d2 : d0;
    const unsigned dB = h ? 0x3F803F80u : d1;   // (1,1) bf16 | dim1
    bq.u.x = dA;
    bq.u.y = dA;
    bq.u.z = dB;
    bq.u.w = h ? 0u : dB;
    return bq;
}

// A fragment-half (points), built on the fly: ~28 VALU ops per point.
// half 0: {pk(h0,h0), pk(l0,l0), pk(h1,h1), pk(l1,l1)}
// half 1: {pk(h2,h2), pk(l2,l2), pk(sh,sl), 0}
__device__ inline FragU make_afrag(const float* __restrict__ p3, int h) {
    const float p0 = p3[0], p1 = p3[1], p2 = p3[2];
    const float s  = fmaf(p0, p0, fmaf(p1, p1, p2 * p2));
    unsigned h0, l0, h1, l1, h2, l2;
    split_rep(-2.0f * p0, h0, l0);
    split_rep(-2.0f * p1, h1, l1);
    split_rep(-2.0f * p2, h2, l2);
    const unsigned us = __float_as_uint(s) & 0xFFFF0000u;
    const unsigned rs = __float_as_uint(s - __uint_as_float(us)) & 0xFFFF0000u;
    const unsigned shsl = (us >> 16) | rs;      // pk(sh, sl)
    FragU fa;
    fa.u.x = h ? h2 : h0;
    fa.u.y = h ? l2 : l0;
    fa.u.z = h ? shsl : h1;
    fa.u.w = h ? 0u : l1;
    return fa;
}

__global__ __launch_bounds__(256, 2) void nn_kernel(const float* __restrict__ input,
                                                    const float* __restrict__ point,
                                                    float* __restrict__ out) {
    const int bid   = blockIdx.x;
    const int qtile = bid % QTILES;
    const int b     = bid / QTILES;
    const int tid   = threadIdx.x;
    const int wave  = tid >> 6;
    const int lane  = tid & 63;
    const int col   = lane & 31;       // A: point row in tile; B: query col
    const int h     = lane >> 5;       // k-half

    // All 4 waves share the same 64 queries (2 column fragments).
    const int q0 = qtile * QB + col;
    const int q1 = q0 + 32;
    float sq_a0, sq_a1;
    const FragU b0 = make_bfrag(input + ((size_t)b * N + q0) * 3, h, sq_a0);
    const FragU b1 = make_bfrag(input + ((size_t)b * N + q1) * 3, h, sq_a1);

    // Waves split the point dimension: wave w owns points [w*MPW, (w+1)*MPW).
    const float* __restrict__ pbase = point + ((size_t)b * M + wave * MPW) * 3;

    f32x16 cz, rmin0, rmin1;
#pragma unroll
    for (int i = 0; i < 16; ++i) { cz[i] = 0.0f; rmin0[i] = 1e30f; rmin1[i] = 1e30f; }

    for (int t = 0; t < TILES; t += 2) {
        const FragU fa0 = make_afrag(pbase + 3 * (t * 32 + col), h);
        const FragU fa1 = make_afrag(pbase + 3 * ((t + 1) * 32 + col), h);
        f32x16 acc00 = __builtin_amdgcn_mfma_f32_32x32x16_bf16(fa0.b, b0.b, cz, 0, 0, 0);
        f32x16 acc01 = __builtin_amdgcn_mfma_f32_32x32x16_bf16(fa0.b, b1.b, cz, 0, 0, 0);
        f32x16 acc10 = __builtin_amdgcn_mfma_f32_32x32x16_bf16(fa1.b, b0.b, cz, 0, 0, 0);
        f32x16 acc11 = __builtin_amdgcn_mfma_f32_32x32x16_bf16(fa1.b, b1.b, cz, 0, 0, 0);
#pragma unroll
        for (int i = 0; i < 16; ++i) {
            rmin0[i] = fminf(rmin0[i], fminf(acc00[i], acc10[i]));   // v_min3_f32
            rmin1[i] = fminf(rmin1[i], fminf(acc01[i], acc11[i]));   // v_min3_f32
        }
    }

    // Per-wave fold: in-lane (16 rows) + cross-half shuffle (other 16 rows).
    float m0 = rmin0[0], m1 = rmin1[0];
#pragma unroll
    for (int i = 1; i < 16; ++i) { m0 = fminf(m0, rmin0[i]); m1 = fminf(m1, rmin1[i]); }
    m0 = fminf(m0, __shfl_xor(m0, 32, 64));
    m1 = fminf(m1, __shfl_xor(m1, 32, 64));

    // Cross-wave reduce in LDS (1 KB), then ONE direct store per query.
    __shared__ float red[WAVES][QB];
    if (lane < 32) {
        red[wave][col]      = m0;
        red[wave][col + 32] = m1;
    }
    __syncthreads();
    if (tid < QB) {
        // thread tid (wave 0, lane tid): tid<32 -> its q0 == qbase+tid,
        // tid>=32 -> its q1 == qbase+32+(tid-32) == qbase+tid.
        const float m = fminf(fminf(red[0][tid], red[1][tid]),
                              fminf(red[2][tid], red[3][tid]));
        const float sq = (tid < 32) ? sq_a0 : sq_a1;
        out[(size_t)b * N + (size_t)qtile * QB + tid] = fmaxf(m + sq, 0.0f);
    }
}

extern "C" void kernel_launch(void* const* d_in, const int* in_sizes, int n_in,
                              void* d_out, int out_size, void* d_ws, size_t ws_size,
                              hipStream_t stream) {
    const float* input = (const float*)d_in[0];   // [B, N, 3] fp32
    const float* point = (const float*)d_in[1];   // [B, M, 3] fp32
    float* out         = (float*)d_out;           // [B, N] fp32

    (void)d_ws; (void)ws_size;                    // workspace intentionally unused

    nn_kernel<<<B * QTILES, 256, 0, stream>>>(input, point, out);
}

// Round 2
// 65.168 us; speedup vs baseline: 1.1044x; 1.1044x over previous
//
#include <hip/hip_runtime.h>

// Problem constants (from setup_inputs): B=4, N=8192, M=8192, D=3, fp32.
constexpr int B = 4;
constexpr int N = 8192;
constexpr int M = 8192;

constexpr int QPW     = 64;            // queries per wave (2 B-fragments)
constexpr int WAVES   = 4;             // waves per block
constexpr int QB      = QPW * WAVES;   // 256 queries per block
constexpr int QTILES  = N / QB;        // 32
constexpr int PCHUNKS = 16;            // point split -> grid 2048 = 8 blocks/CU
constexpr int CHUNK   = M / PCHUNKS;   // 512 points per block
constexpr int PTILES  = CHUNK / 32;    // 16 A-tiles, 32 mfmas per wave

typedef __bf16 bf16x8 __attribute__((ext_vector_type(8)));
typedef float  f32x16 __attribute__((ext_vector_type(16)));

union FragU { uint4 u; bf16x8 b; };

// fp32 -> bf16 bits, round-to-nearest-even (finite inputs only).
__device__ __host__ inline unsigned f2bf(float x) {
    unsigned u = __float_as_uint(x);
    return (u + 0x7FFFu + ((u >> 16) & 1u)) >> 16;
}
__device__ inline float bf2f(unsigned b) { return __uint_as_float(b << 16); }
__device__ inline unsigned pk(unsigned lo, unsigned hi) { return lo | (hi << 16); }

// ---------------------------------------------------------------------------
// Architecture note (round 1 experiment): the harness re-poisons the 256 MiB
// d_ws EVERY timed iteration (~40 us fillBufferAligned at 84% HBM peak) even
// when d_ws is never referenced -> using d_ws for wtab is FREE. The fused
// no-workspace variant (rebuild A-frags in-loop) measured +5.7 us WORSE.
// So: keep the two-kernel wtab design, attack main-kernel latency hiding.
//
// K-slot packing (mfma_f32_32x32x16_bf16, A rows = points, B cols = queries):
//   k0..3 : A=(ph0,ph0,pl0,pl0)  B=(ah0,al0,ah0,al0)  -> (ph0+pl0)(ah0+al0)
//   k4..7 : dim 1   k8..11: dim 2   k12,13: A=(sh,sl) B=(1,1) -> ||p||^2
//   k14,15: 0         (p' = -2p, everything split bf16 hi/lo)
// acc[row=point][col=query] = -2 a.p + ||p||^2   (absmax 7.8e-3, verified).
// ---------------------------------------------------------------------------

// Prep: pack each point's two A-fragment halves into wtab (32 B/point, 1 MB)
// AND initialize out to 0x7F7F7F7F (uint order == float order for
// non-negative floats, so atomicMin(uint) implements float min). B*M == B*N.
__global__ __launch_bounds__(256) void prep_kernel(const float* __restrict__ point,
                                                   uint4* __restrict__ wtab,
                                                   unsigned int* __restrict__ out) {
    int i = blockIdx.x * 256 + threadIdx.x;   // 0 .. B*M-1
    if (i >= B * M) return;
    const float p0 = point[3 * i + 0];
    const float p1 = point[3 * i + 1];
    const float p2 = point[3 * i + 2];
    const float v0 = -2.0f * p0, v1 = -2.0f * p1, v2 = -2.0f * p2;
    const unsigned h0 = f2bf(v0), l0 = f2bf(v0 - bf2f(h0));
    const unsigned h1 = f2bf(v1), l1 = f2bf(v1 - bf2f(h1));
    const unsigned h2 = f2bf(v2), l2 = f2bf(v2 - bf2f(h2));
    const float s = fmaf(p0, p0, fmaf(p1, p1, p2 * p2));
    const unsigned sh = f2bf(s), sl = f2bf(s - bf2f(sh));
    uint4 f0, f1;
    f0.x = pk(h0, h0); f0.y = pk(l0, l0); f0.z = pk(h1, h1); f0.w = pk(l1, l1); // k0..7
    f1.x = pk(h2, h2); f1.y = pk(l2, l2); f1.z = pk(sh, sl); f1.w = 0;          // k8..15
    wtab[2 * i + 0] = f0;
    wtab[2 * i + 1] = f1;
    out[i] = 0x7F7F7F7Fu;
}

// Build the B fragment for query index q (this lane's column).
__device__ inline FragU make_bfrag(const float* __restrict__ input,
                                   int b, int q, int h, float& sq_a) {
    const float* a = input + ((size_t)b * N + q) * 3;
    const float a0 = a[0], a1 = a[1], a2 = a[2];
    sq_a = fmaf(a0, a0, fmaf(a1, a1, a2 * a2));
    const unsigned ah0 = f2bf(a0), al0 = f2bf(a0 - bf2f(ah0));
    const unsigned ah1 = f2bf(a1), al1 = f2bf(a1 - bf2f(ah1));
    const unsigned ah2 = f2bf(a2), al2 = f2bf(a2 - bf2f(ah2));
    FragU bq;
    const unsigned dA = h ? pk(ah2, al2) : pk(ah0, al0);
    const unsigned dB = h ? 0x3F803F80u  : pk(ah1, al1);   // (1,1) bf16 | dim1
    bq.u.x = dA;
    bq.u.y = dA;
    bq.u.z = dB;
    bq.u.w = h ? 0u : dB;
    return bq;
}

// Main: one wave = 64 queries (2 B frags) vs its 512-point chunk.
// Round-2 changes vs the 66.3 us version:
//  * within-acc min3 folding: rmin shrinks to 8 regs per B-frag, only 1-2
//    accs live at a time (was 4), each fold depends on ONE mfma -> deeper
//    pipelining by the scheduler.
//  * __launch_bounds__(256, 4): VGPR <= 128 -> 4 waves/SIMD (was 3) to
//    hide A-load (L1/L2) and mfma latency.
//  * #pragma unroll 2: 2-deep A-load prefetch across iterations.
__global__ __launch_bounds__(256, 4) void main_kernel(const float* __restrict__ input,
                                                      const uint4* __restrict__ wtab,
                                                      unsigned int* __restrict__ out) {
    const int bid    = blockIdx.x;
    const int pchunk = bid % PCHUNKS;
    const int qtile  = (bid / PCHUNKS) % QTILES;
    const int b      = bid / (PCHUNKS * QTILES);
    const int tid    = threadIdx.x;
    const int wave   = tid >> 6;
    const int lane   = tid & 63;
    const int col    = lane & 31;          // A: point row in tile; B: query col
    const int h      = lane >> 5;          // k-half

    const int q0 = qtile * QB + wave * QPW + col;        // first query set
    const int q1 = q0 + 32;                              // second query set
    float sq_a0, sq_a1;
    const FragU b0 = make_bfrag(input, b, q0, h, sq_a0);
    const FragU b1 = make_bfrag(input, b, q1, h, sq_a1);

    const uint4* __restrict__ wp =
        wtab + ((size_t)b * M + (size_t)pchunk * CHUNK) * 2;

    f32x16 cz;
    float r0[8], r1[8];
#pragma unroll
    for (int i = 0; i < 16; ++i) cz[i] = 0.0f;
#pragma unroll
    for (int i = 0; i < 8; ++i) { r0[i] = 1e30f; r1[i] = 1e30f; }

#pragma unroll 2
    for (int t = 0; t < PTILES; t += 2) {
        FragU fa0, fa1;
        fa0.u = wp[((t * 32 + col) << 1) + h];
        fa1.u = wp[(((t + 1) * 32 + col) << 1) + h];
        // Two independent mfmas in flight, then fold each within-acc:
        // r[j] = min3(r[j], acc[2j], acc[2j+1]) -> 8 v_min3 per mfma (optimal),
        // each fold depends on a single mfma result.
        {
            f32x16 accA = __builtin_amdgcn_mfma_f32_32x32x16_bf16(fa0.b, b0.b, cz, 0, 0, 0);
            f32x16 accB = __builtin_amdgcn_mfma_f32_32x32x16_bf16(fa1.b, b0.b, cz, 0, 0, 0);
#pragma unroll
            for (int j = 0; j < 8; ++j)
                r0[j] = fminf(fminf(r0[j], accA[2 * j]), accA[2 * j + 1]);
#pragma unroll
            for (int j = 0; j < 8; ++j)
                r0[j] = fminf(fminf(r0[j], accB[2 * j]), accB[2 * j + 1]);
        }
        {
            f32x16 accA = __builtin_amdgcn_mfma_f32_32x32x16_bf16(fa0.b, b1.b, cz, 0, 0, 0);
            f32x16 accB = __builtin_amdgcn_mfma_f32_32x32x16_bf16(fa1.b, b1.b, cz, 0, 0, 0);
#pragma unroll
            for (int j = 0; j < 8; ++j)
                r1[j] = fminf(fminf(r1[j], accA[2 * j]), accA[2 * j + 1]);
#pragma unroll
            for (int j = 0; j < 8; ++j)
                r1[j] = fminf(fminf(r1[j], accB[2 * j]), accB[2 * j + 1]);
        }
    }

    // Epilogue: fold 8 -> 1 in-lane (v_min3 tree), then cross-half shuffle.
    float m0 = fminf(fminf(r0[0], r0[1]), r0[2]);
    m0 = fminf(fminf(m0, r0[3]), r0[4]);
    m0 = fminf(fminf(m0, r0[5]), r0[6]);
    m0 = fminf(m0, r0[7]);
    float m1 = fminf(fminf(r1[0], r1[1]), r1[2]);
    m1 = fminf(fminf(m1, r1[3]), r1[4]);
    m1 = fminf(fminf(m1, r1[5]), r1[6]);
    m1 = fminf(m1, r1[7]);
    m0 = fminf(m0, __shfl_xor(m0, 32, 64));
    m1 = fminf(m1, __shfl_xor(m1, 32, 64));

    if (lane < 32) {
        atomicMin(&out[(size_t)b * N + q0], __float_as_uint(fmaxf(m0 + sq_a0, 0.0f)));
        atomicMin(&out[(size_t)b * N + q1], __float_as_uint(fmaxf(m1 + sq_a1, 0.0f)));
    }
}

extern "C" void kernel_launch(void* const* d_in, const int* in_sizes, int n_in,
                              void* d_out, int out_size, void* d_ws, size_t ws_size,
                              hipStream_t stream) {
    const float* input = (const float*)d_in[0];   // [B, N, 3] fp32
    const float* point = (const float*)d_in[1];   // [B, M, 3] fp32
    unsigned int* out  = (unsigned int*)d_out;    // [B, N] fp32 viewed as uint

    uint4* wtab = (uint4*)d_ws;                   // 1 MB packed A-fragment table

    const int prep_grid = (B * M + 255) / 256;        // 128 blocks
    const int main_grid = B * QTILES * PCHUNKS;       // 2048 blocks

    prep_kernel<<<prep_grid, 256, 0, stream>>>(point, wtab, out);
    main_kernel<<<main_grid, 256, 0, stream>>>(input, wtab, out);
}